// Round 5
// baseline (412.619 us; speedup 1.0000x reference)
//
#include <hip/hip_runtime.h>
#include <hip/hip_bf16.h>
#include <stdint.h>

#define GN 8192
#define GF 128
#define NEG_SLOPE 0.2f
#define L2E 1.4426950408889634f   // log2(e): s_src/s_dst pre-scaled so k2 uses raw v_exp_f32
#define BIGL 1024.0f              // exp2(x - 1024 + adj*1024): masked entries underflow to exactly 0.0f

typedef __attribute__((ext_vector_type(8))) short bf16x8;
typedef __attribute__((ext_vector_type(4))) float f32x4;

__device__ __forceinline__ unsigned fkey(float f) {
    unsigned u = __float_as_uint(f);
    return (u & 0x80000000u) ? ~u : (u | 0x80000000u);
}
__device__ __forceinline__ float funkey(unsigned k) {
    unsigned b = (k & 0x80000000u) ? (k & 0x7FFFFFFFu) : ~k;
    return __uint_as_float(b);
}
__device__ __forceinline__ unsigned short bf16rne(float f) {
    unsigned u = __float_as_uint(f);
    return (unsigned short)((u + 0x7FFFu + ((u >> 16) & 1u)) >> 16);
}
// two fp32 -> packed bf16 in one instruction (guide m240/m214v22-verified; lo=S0, hi=S1)
__device__ __forceinline__ unsigned cvtpk(float lo, float hi) {
    unsigned r; asm("v_cvt_pk_bf16_f32 %0, %1, %2" : "=v"(r) : "v"(lo), "v"(hi)); return r;
}
__device__ __forceinline__ float exp2a(float x) {
#if __has_builtin(__builtin_amdgcn_exp2f)
    return __builtin_amdgcn_exp2f(x);   // raw v_exp_f32 (2^x)
#else
    return exp2f(x);
#endif
}
// non-temporal 16B load: adj is strictly read-once streaming; don't thrash L2/LLC
__device__ __forceinline__ f32x4 ldnt4(const float* p) {
    return __builtin_nontemporal_load((const f32x4*)p);
}

// K1: x' = x@W + b (fp32); writes xpt in SWIZZLED MFMA-fragment order:
// elem(j, f) at [chunk=j/64][fg=f/16][half=(j%64)/32][q4=(j%32)/8][m16=f%16][jj=j%8]
// so a k2 B-frag load is a contiguous 16B/lane transfer in exact fragment order.
// s_src/s_dst are written PRE-SCALED by log2(e) so k2 uses raw v_exp_f32.
__global__ __launch_bounds__(256) void gat_k1(
    const float* __restrict__ x, const float* __restrict__ w,
    const float* __restrict__ bias, const float* __restrict__ phi,
    unsigned short* __restrict__ xpt, float* __restrict__ s_src,
    float* __restrict__ s_dst)
{
    __shared__ float Xl[16][132];
    __shared__ float Wl[32][132];
    __shared__ unsigned short TR[128][24];
    const int tid = threadIdx.x;
    const int i0 = blockIdx.x * 16;

    #pragma unroll
    for (int q = 0; q < 2; q++) {                 // stage 16x128 x tile
        int flat = (q * 256 + tid) * 4;
        int r = flat >> 7, c = flat & 127;
        *(float4*)&Xl[r][c] = *(const float4*)&x[(size_t)(i0 + r) * GF + c];
    }

    const int rid = tid >> 5;          // 0..7 -> rows 2rid, 2rid+1
    const int c0  = (tid & 31) * 4;    // 4 consecutive features

    float acc[2][4] = {};
    for (int kc = 0; kc < 4; kc++) {   // W staged in 32-row chunks
        __syncthreads();
        #pragma unroll
        for (int q = 0; q < 4; q++) {
            int flat = (q * 256 + tid) * 4;
            int kk = flat >> 7, c = flat & 127;
            *(float4*)&Wl[kk][c] = *(const float4*)&w[(size_t)(kc * 32 + kk) * GF + c];
        }
        __syncthreads();
        #pragma unroll
        for (int k = 0; k < 32; k++) {
            float4 wv = *(const float4*)&Wl[k][c0];
            #pragma unroll
            for (int m = 0; m < 2; m++) {
                float xv = Xl[rid * 2 + m][kc * 32 + k];
                acc[m][0] = fmaf(xv, wv.x, acc[m][0]);
                acc[m][1] = fmaf(xv, wv.y, acc[m][1]);
                acc[m][2] = fmaf(xv, wv.z, acc[m][2]);
                acc[m][3] = fmaf(xv, wv.w, acc[m][3]);
            }
        }
    }

    float b4[4], p1[4], p2[4];
    #pragma unroll
    for (int q = 0; q < 4; q++) {
        b4[q] = bias[c0 + q];
        p1[q] = phi[c0 + q];
        p2[q] = phi[GF + c0 + q];
    }
    #pragma unroll
    for (int m = 0; m < 2; m++) {
        float ps = 0.f, pd = 0.f;
        #pragma unroll
        for (int q = 0; q < 4; q++) {
            float v = acc[m][q] + b4[q];
            ps = fmaf(v, p1[q], ps);
            pd = fmaf(v, p2[q], pd);
            TR[c0 + q][rid * 2 + m] = bf16rne(v);   // LDS transpose staging
        }
        #pragma unroll
        for (int s = 16; s >= 1; s >>= 1) {
            ps += __shfl_xor(ps, s, 64);
            pd += __shfl_xor(pd, s, 64);
        }
        if ((tid & 31) == 0) {
            s_src[i0 + rid * 2 + m] = ps * L2E;   // log2-domain
            s_dst[i0 + rid * 2 + m] = pd * L2E;
        }
    }
    __syncthreads();
    {   // swizzled store: thread -> (feature f, node-octet oct), 16B each
        const int f = tid >> 1, oct = tid & 1;
        const int fg = f >> 4, mf = f & 15;
        const int chunk = i0 >> 6;
        const int half  = (i0 >> 5) & 1;
        const int q4b   = (((i0 & 31) >> 3)) + oct;   // {0,2}+oct
        const size_t base = (size_t)chunk * 8192 + fg * 1024 + half * 512
                          + q4b * 128 + mf * 8;
        *(uint4*)&xpt[base] = *(const uint4*)&TR[f][oct * 8];
    }
}

// K1b: D = max(s_dst). 8 blocks -> only 8 same-address atomics.
// (s_dst is log2e-scaled; max commutes with a positive scale.)
__global__ __launch_bounds__(256) void gat_k1b(
    const float* __restrict__ s_dst, unsigned* __restrict__ Dkey)
{
    __shared__ float sm[4];
    const int tid = threadIdx.x;
    const int idx = (blockIdx.x * 256 + tid) * 4;
    float4 v = *(const float4*)&s_dst[idx];
    float m = fmaxf(fmaxf(v.x, v.y), fmaxf(v.z, v.w));
    #pragma unroll
    for (int s = 32; s >= 1; s >>= 1) m = fmaxf(m, __shfl_xor(m, s, 64));
    if ((tid & 63) == 0) sm[tid >> 6] = m;
    __syncthreads();
    if (tid == 0) {
        m = fmaxf(fmaxf(sm[0], sm[1]), fmaxf(sm[2], sm[3]));
        atomicMax(Dkey, fkey(m));
    }
}

// K2: barrier-free flash GAT, B-frags direct global->VGPR, SINGLE-buffered.
// Dropping the B ping-pong frees 64 VGPRs; __launch_bounds__(256,3) pins the
// allocator at <=170 VGPR -> 3 waves/SIMD (vs 2) for +50% latency hiding.
// B-frag loads issue at body start; the ~160-cycle P-math window plus cross-
// wave TLP covers their L2-hit latency. All ordering is register dataflow
// (hardware dep-tracked) -- no vmcnt race surface.
__global__ __launch_bounds__(256, 3) void gat_k2(
    const float* __restrict__ adj, const unsigned short* __restrict__ xpt,
    const float* __restrict__ s_src, const float* __restrict__ s_dst,
    const unsigned* __restrict__ Dkey, float* __restrict__ out)
{
    __shared__ unsigned short Pt[4][640];    // per-wave P tile, row stride 40
    __shared__ float Zl[4][16];
    __shared__ float Ol[4][16][33];          // epilogue quarter-feature buffer

    const int tid  = threadIdx.x;
    const int wave = tid >> 6, lane = tid & 63;
    const int m16  = lane & 15, q4 = lane >> 4;
    const int r    = lane >> 2;        // P row this lane computes (0..15)
    const int c8   = (lane & 3) * 8;   // col octet within 32-col chunk
    const int i0   = blockIdx.x * 16;
    const int irow = i0 + r;

    const float D  = funkey(*Dkey);
    const float si = s_src[irow];                    // log2e-scaled
    const float t0 = si + D;
    const float mneg = -fmaxf(t0, NEG_SLOPE * t0);   // -Mi bound (log2 domain)
    const float base = mneg - BIGL;

    const float* arow = adj + (size_t)irow * GN + c8;
    unsigned short* Pw = Pt[wave];
    const int cw = wave * 2048;        // wave's j-range start

    f32x4 acc[8];
    #pragma unroll
    for (int fg = 0; fg < 8; fg++) acc[fg] = (f32x4){0.f, 0.f, 0.f, 0.f};
    float z = 0.f;

    // ---- prologue: adj/s_dst regs for t=0 (A) and t=1 (B)
    f32x4 aA0 = ldnt4(arow + cw);
    f32x4 aA1 = ldnt4(arow + cw + 4);
    f32x4 dA0 = *(const f32x4*)(s_dst + cw + c8);
    f32x4 dA1 = *(const f32x4*)(s_dst + cw + c8 + 4);
    f32x4 aB0 = ldnt4(arow + cw + 32);
    f32x4 aB1 = ldnt4(arow + cw + 36);
    f32x4 dB0 = *(const f32x4*)(s_dst + cw + 32 + c8);
    f32x4 dB1 = *(const f32x4*)(s_dst + cw + 32 + c8 + 4);

    auto body = [&](int t, f32x4& pa0, f32x4& pa1, f32x4& pd0, f32x4& pd1) {
        const int cbase = cw + t * 32;
        const f32x4 a0 = pa0, a1 = pa1, d0 = pd0, d1 = pd1;

        // B-frags for THIS chunk: issue first, consumed after P-math
        bf16x8 Bf[8];
        {
            const unsigned short* src = xpt + (size_t)(cbase >> 6) * 8192
                                      + (size_t)((cbase >> 5) & 1) * 512 + lane * 8;
            #pragma unroll
            for (int fg = 0; fg < 8; fg++)
                Bf[fg] = *(const bf16x8*)(src + fg * 1024);
        }
        if (t + 2 < 64) {   // adj + s_dst register prefetch for t+2
            const int pb = cbase + 64;
            pa0 = ldnt4(arow + pb);
            pa1 = ldnt4(arow + pb + 4);
            pd0 = *(const f32x4*)(s_dst + pb + c8);
            pd1 = *(const f32x4*)(s_dst + pb + c8 + 4);
        }

        // P: row irow, cols cbase+c8 .. +8 — log2 domain, raw v_exp_f32
        float p[8];
        #pragma unroll
        for (int q = 0; q < 8; q++) {
            const float sd = (q < 4) ? d0[q] : d1[q - 4];
            const float aq = (q < 4) ? a0[q] : a1[q - 4];
            const float tt = si + sd;
            const float lr = fmaxf(tt, NEG_SLOPE * tt);
            float zz = fmaf(aq, BIGL, lr + base);     // masked -> exp2 underflow
            if (cbase + c8 + q == irow) zz = lr + mneg;   // self-loop kept
            p[q] = exp2a(zz);
            z += p[q];
        }
        uint4 pk;
        pk.x = cvtpk(p[0], p[1]); pk.y = cvtpk(p[2], p[3]);
        pk.z = cvtpk(p[4], p[5]); pk.w = cvtpk(p[6], p[7]);
        *(uint4*)&Pw[r * 40 + c8] = pk;          // 16B-aligned (stride 80B)

        // A-frag via same-wave LDS transpose (lgkm-only), B-frags from regs
        const bf16x8 af = *(const bf16x8*)&Pw[m16 * 40 + q4 * 8];
        #pragma unroll
        for (int fg = 0; fg < 8; fg++)
            acc[fg] = __builtin_amdgcn_mfma_f32_16x16x32_bf16(af, Bf[fg], acc[fg], 0, 0, 0);
    };

    #pragma unroll 1
    for (int t = 0; t < 64; t += 2) {
        body(t,     aA0, aA1, dA0, dA1);
        body(t + 1, aB0, aB1, dB0, dB1);
    }

    // Z: lanes 4r..4r+3 hold row r partials for this wave
    z += __shfl_xor(z, 1, 64);
    z += __shfl_xor(z, 2, 64);
    if ((lane & 3) == 0) Zl[wave][r] = z;
    __syncthreads();

    const int er = tid >> 4;            // epilogue row 0..15
    const int ef = (tid & 15) * 2;      // feat pair within 32-feat quarter
    const float zinv = 1.0f / (Zl[0][er] + Zl[1][er] + Zl[2][er] + Zl[3][er]);

    #pragma unroll
    for (int qp = 0; qp < 4; qp++) {    // cross-wave O reduce, 32 feats/pass
        #pragma unroll
        for (int g = 0; g < 2; g++) {   // C layout: col=lane&15, row=q4*4+v
            const int fg = qp * 2 + g;
            #pragma unroll
            for (int v = 0; v < 4; v++)
                Ol[wave][q4 * 4 + v][g * 16 + m16] = acc[fg][v];
        }
        __syncthreads();
        float o0 = 0.f, o1 = 0.f;
        #pragma unroll
        for (int wv = 0; wv < 4; wv++) {
            o0 += Ol[wv][er][ef];
            o1 += Ol[wv][er][ef + 1];
        }
        *(float2*)&out[(size_t)(i0 + er) * GF + qp * 32 + ef] =
            make_float2(o0 * zinv, o1 * zinv);
        __syncthreads();
    }
}

extern "C" void kernel_launch(void* const* d_in, const int* in_sizes, int n_in,
                              void* d_out, int out_size, void* d_ws, size_t ws_size,
                              hipStream_t stream)
{
    (void)in_sizes; (void)n_in; (void)out_size; (void)ws_size;
    const float* adj  = (const float*)d_in[0];
    const float* x    = (const float*)d_in[1];
    const float* w    = (const float*)d_in[2];
    const float* bias = (const float*)d_in[3];
    const float* phi  = (const float*)d_in[4];
    float* out = (float*)d_out;

    char* ws = (char*)d_ws;
    unsigned short* xpt = (unsigned short*)ws;             // 2 MB bf16 x' swizzled
    float* s_src = (float*)(ws + (size_t)GF * GN * 2);     // 32 KB (log2e-scaled)
    float* s_dst = s_src + GN;                             // 32 KB (log2e-scaled)
    unsigned* Dkey = (unsigned*)(s_dst + GN);              // 4 B

    hipMemsetAsync(Dkey, 0, sizeof(unsigned), stream);
    gat_k1 <<<GN / 16, 256, 0, stream>>>(x, w, bias, phi, xpt, s_src, s_dst);
    gat_k1b<<<8, 256, 0, stream>>>(s_dst, Dkey);
    gat_k2 <<<GN / 16, 256, 0, stream>>>(adj, xpt, s_src, s_dst, Dkey, out);
}

// Round 6
// 408.306 us; speedup vs baseline: 1.0106x; 1.0106x over previous
//
#include <hip/hip_runtime.h>
#include <hip/hip_bf16.h>
#include <stdint.h>

#define GN 8192
#define GF 128
#define NEG_SLOPE 0.2f
#define L2E 1.4426950408889634f   // log2(e): s_src/s_dst pre-scaled so k2 uses raw v_exp_f32
#define BIGL 1024.0f              // exp2(x - 1024 + adj*1024): masked entries underflow to exactly 0.0f

typedef __attribute__((ext_vector_type(8))) short bf16x8;
typedef __attribute__((ext_vector_type(4))) float f32x4;

__device__ __forceinline__ unsigned fkey(float f) {
    unsigned u = __float_as_uint(f);
    return (u & 0x80000000u) ? ~u : (u | 0x80000000u);
}
__device__ __forceinline__ float funkey(unsigned k) {
    unsigned b = (k & 0x80000000u) ? (k & 0x7FFFFFFFu) : ~k;
    return __uint_as_float(b);
}
__device__ __forceinline__ unsigned short bf16rne(float f) {
    unsigned u = __float_as_uint(f);
    return (unsigned short)((u + 0x7FFFu + ((u >> 16) & 1u)) >> 16);
}
// two fp32 -> packed bf16 in one instruction (guide m240/m214v22-verified; lo=S0, hi=S1)
__device__ __forceinline__ unsigned cvtpk(float lo, float hi) {
    unsigned r; asm("v_cvt_pk_bf16_f32 %0, %1, %2" : "=v"(r) : "v"(lo), "v"(hi)); return r;
}
__device__ __forceinline__ float exp2a(float x) {
#if __has_builtin(__builtin_amdgcn_exp2f)
    return __builtin_amdgcn_exp2f(x);   // raw v_exp_f32 (2^x)
#else
    return exp2f(x);
#endif
}
// non-temporal 16B load: adj is strictly read-once streaming; don't thrash L2/LLC
__device__ __forceinline__ f32x4 ldnt4(const float* p) {
    return __builtin_nontemporal_load((const f32x4*)p);
}

// K1: x' = x@W + b (fp32); writes xpt in SWIZZLED MFMA-fragment order:
// elem(j, f) at [chunk=j/64][fg=f/16][half=(j%64)/32][q4=(j%32)/8][m16=f%16][jj=j%8]
// so a k2 B-frag load is a contiguous 16B/lane transfer in exact fragment order.
// s_src/s_dst are written PRE-SCALED by log2(e) so k2 uses raw v_exp_f32.
__global__ __launch_bounds__(256) void gat_k1(
    const float* __restrict__ x, const float* __restrict__ w,
    const float* __restrict__ bias, const float* __restrict__ phi,
    unsigned short* __restrict__ xpt, float* __restrict__ s_src,
    float* __restrict__ s_dst)
{
    __shared__ float Xl[16][132];
    __shared__ float Wl[32][132];
    __shared__ unsigned short TR[128][24];
    const int tid = threadIdx.x;
    const int i0 = blockIdx.x * 16;

    #pragma unroll
    for (int q = 0; q < 2; q++) {                 // stage 16x128 x tile
        int flat = (q * 256 + tid) * 4;
        int r = flat >> 7, c = flat & 127;
        *(float4*)&Xl[r][c] = *(const float4*)&x[(size_t)(i0 + r) * GF + c];
    }

    const int rid = tid >> 5;          // 0..7 -> rows 2rid, 2rid+1
    const int c0  = (tid & 31) * 4;    // 4 consecutive features

    float acc[2][4] = {};
    for (int kc = 0; kc < 4; kc++) {   // W staged in 32-row chunks
        __syncthreads();
        #pragma unroll
        for (int q = 0; q < 4; q++) {
            int flat = (q * 256 + tid) * 4;
            int kk = flat >> 7, c = flat & 127;
            *(float4*)&Wl[kk][c] = *(const float4*)&w[(size_t)(kc * 32 + kk) * GF + c];
        }
        __syncthreads();
        #pragma unroll
        for (int k = 0; k < 32; k++) {
            float4 wv = *(const float4*)&Wl[k][c0];
            #pragma unroll
            for (int m = 0; m < 2; m++) {
                float xv = Xl[rid * 2 + m][kc * 32 + k];
                acc[m][0] = fmaf(xv, wv.x, acc[m][0]);
                acc[m][1] = fmaf(xv, wv.y, acc[m][1]);
                acc[m][2] = fmaf(xv, wv.z, acc[m][2]);
                acc[m][3] = fmaf(xv, wv.w, acc[m][3]);
            }
        }
    }

    float b4[4], p1[4], p2[4];
    #pragma unroll
    for (int q = 0; q < 4; q++) {
        b4[q] = bias[c0 + q];
        p1[q] = phi[c0 + q];
        p2[q] = phi[GF + c0 + q];
    }
    #pragma unroll
    for (int m = 0; m < 2; m++) {
        float ps = 0.f, pd = 0.f;
        #pragma unroll
        for (int q = 0; q < 4; q++) {
            float v = acc[m][q] + b4[q];
            ps = fmaf(v, p1[q], ps);
            pd = fmaf(v, p2[q], pd);
            TR[c0 + q][rid * 2 + m] = bf16rne(v);   // LDS transpose staging
        }
        #pragma unroll
        for (int s = 16; s >= 1; s >>= 1) {
            ps += __shfl_xor(ps, s, 64);
            pd += __shfl_xor(pd, s, 64);
        }
        if ((tid & 31) == 0) {
            s_src[i0 + rid * 2 + m] = ps * L2E;   // log2-domain
            s_dst[i0 + rid * 2 + m] = pd * L2E;
        }
    }
    __syncthreads();
    {   // swizzled store: thread -> (feature f, node-octet oct), 16B each
        const int f = tid >> 1, oct = tid & 1;
        const int fg = f >> 4, mf = f & 15;
        const int chunk = i0 >> 6;
        const int half  = (i0 >> 5) & 1;
        const int q4b   = (((i0 & 31) >> 3)) + oct;   // {0,2}+oct
        const size_t base = (size_t)chunk * 8192 + fg * 1024 + half * 512
                          + q4b * 128 + mf * 8;
        *(uint4*)&xpt[base] = *(const uint4*)&TR[f][oct * 8];
    }
}

// K1b: D = max(s_dst). 8 blocks -> only 8 same-address atomics.
// (s_dst is log2e-scaled; max commutes with a positive scale.)
__global__ __launch_bounds__(256) void gat_k1b(
    const float* __restrict__ s_dst, unsigned* __restrict__ Dkey)
{
    __shared__ float sm[4];
    const int tid = threadIdx.x;
    const int idx = (blockIdx.x * 256 + tid) * 4;
    float4 v = *(const float4*)&s_dst[idx];
    float m = fmaxf(fmaxf(v.x, v.y), fmaxf(v.z, v.w));
    #pragma unroll
    for (int s = 32; s >= 1; s >>= 1) m = fmaxf(m, __shfl_xor(m, s, 64));
    if ((tid & 63) == 0) sm[tid >> 6] = m;
    __syncthreads();
    if (tid == 0) {
        m = fmaxf(fmaxf(sm[0], sm[1]), fmaxf(sm[2], sm[3]));
        atomicMax(Dkey, fkey(m));
    }
}

// K2: barrier-free flash GAT, 32-ROW blocks (512 thr, 8 waves, 1 block/CU).
// Each wave covers ALL 32 rows over a 1024-col j-stripe -> every B-frag is
// read once per 32 rows (was once per 16): per-CU L1 traffic for B halves.
// s_dst stripe staged in wave-private LDS once (removes the 16x-redundant
// per-body VMEM stream). adj in depth-2 register ping-pong. Same proven
// fragment layout / P transpose / epilogue as the 16-row version, x2 rows.
__global__ __launch_bounds__(512, 2) void gat_k2(
    const float* __restrict__ adj, const unsigned short* __restrict__ xpt,
    const float* __restrict__ s_src, const float* __restrict__ s_dst,
    const unsigned* __restrict__ Dkey, float* __restrict__ out)
{
    __shared__ unsigned short Pt[8][1280];   // per-wave P tile: [rh*640 + r*40 + c]
    __shared__ float Sl[8][1024];            // per-wave s_dst stripe (32 KB)
    __shared__ float Zl[8][32];
    __shared__ float Ol[8][32][33];          // epilogue quarter-feature buffer

    const int tid  = threadIdx.x;
    const int wave = tid >> 6, lane = tid & 63;
    const int m16  = lane & 15, q4 = lane >> 4;
    const int r    = lane >> 2;        // P row (low half) this lane computes
    const int c8   = (lane & 3) * 8;   // col octet within 32-col chunk
    const int i0   = blockIdx.x * 32;
    const int irL  = i0 + r;           // low row
    const int irH  = irL + 16;         // high row

    const float D   = funkey(*Dkey);
    const float siL = s_src[irL];                      // log2e-scaled
    const float siH = s_src[irH];
    const float tL  = siL + D, tH = siH + D;
    const float mnegL = -fmaxf(tL, NEG_SLOPE * tL);    // -Mi bounds (log2 domain)
    const float mnegH = -fmaxf(tH, NEG_SLOPE * tH);
    const float baseL = mnegL - BIGL;
    const float baseH = mnegH - BIGL;

    const float* arL = adj + (size_t)irL * GN + c8;
    const float* arH = adj + (size_t)irH * GN + c8;
    unsigned short* Pw = Pt[wave];
    float* Sw = Sl[wave];
    const int cw = wave * 1024;        // wave's j-range start (32 chunks)

    // stage s_dst stripe -> wave-private LDS (no sync needed)
    #pragma unroll
    for (int q = 0; q < 4; q++) {
        const int o = q * 256 + lane * 4;
        *(float4*)&Sw[o] = *(const float4*)&s_dst[cw + o];
    }

    f32x4 acc[2][8];
    #pragma unroll
    for (int rh = 0; rh < 2; rh++)
        #pragma unroll
        for (int fg = 0; fg < 8; fg++) acc[rh][fg] = (f32x4){0.f, 0.f, 0.f, 0.f};
    float zL = 0.f, zH = 0.f;

    // ---- prologue: adj regs for t=0 (A) and t=1 (B), both rows
    f32x4 aA0 = ldnt4(arL + cw),      aA1 = ldnt4(arL + cw + 4);
    f32x4 aA2 = ldnt4(arH + cw),      aA3 = ldnt4(arH + cw + 4);
    f32x4 aB0 = ldnt4(arL + cw + 32), aB1 = ldnt4(arL + cw + 36);
    f32x4 aB2 = ldnt4(arH + cw + 32), aB3 = ldnt4(arH + cw + 36);

    auto body = [&](int t, f32x4& pa0, f32x4& pa1, f32x4& pa2, f32x4& pa3) {
        const int cbase = cw + t * 32;
        const f32x4 a0 = pa0, a1 = pa1, a2 = pa2, a3 = pa3;

        // B-frags for THIS chunk: issue first, consumed after P-math
        bf16x8 Bf[8];
        {
            const unsigned short* src = xpt + (size_t)(cbase >> 6) * 8192
                                      + (size_t)((cbase >> 5) & 1) * 512 + lane * 8;
            #pragma unroll
            for (int fg = 0; fg < 8; fg++)
                Bf[fg] = *(const bf16x8*)(src + fg * 1024);
        }
        if (t + 2 < 32) {   // adj register prefetch for t+2, both rows
            const int pb = cbase + 64;
            pa0 = ldnt4(arL + pb); pa1 = ldnt4(arL + pb + 4);
            pa2 = ldnt4(arH + pb); pa3 = ldnt4(arH + pb + 4);
        }

        // s_dst for this chunk from LDS (shared across all 32 rows)
        const f32x4 d0 = *(const f32x4*)&Sw[t * 32 + c8];
        const f32x4 d1 = *(const f32x4*)&Sw[t * 32 + c8 + 4];

        // P: rows irL,irH, cols cbase+c8 .. +8 — log2 domain, raw v_exp_f32
        float pL[8], pH[8];
        #pragma unroll
        for (int q = 0; q < 8; q++) {
            const float sd  = (q < 4) ? d0[q] : d1[q - 4];
            const float aqL = (q < 4) ? a0[q] : a1[q - 4];
            const float aqH = (q < 4) ? a2[q] : a3[q - 4];
            const int   jc  = cbase + c8 + q;
            const float ttL = siL + sd;
            const float lrL = fmaxf(ttL, NEG_SLOPE * ttL);
            float zzL = fmaf(aqL, BIGL, lrL + baseL);
            if (jc == irL) zzL = lrL + mnegL;            // self-loop kept
            pL[q] = exp2a(zzL);
            zL += pL[q];
            const float ttH = siH + sd;
            const float lrH = fmaxf(ttH, NEG_SLOPE * ttH);
            float zzH = fmaf(aqH, BIGL, lrH + baseH);
            if (jc == irH) zzH = lrH + mnegH;
            pH[q] = exp2a(zzH);
            zH += pH[q];
        }
        uint4 pkL, pkH;
        pkL.x = cvtpk(pL[0], pL[1]); pkL.y = cvtpk(pL[2], pL[3]);
        pkL.z = cvtpk(pL[4], pL[5]); pkL.w = cvtpk(pL[6], pL[7]);
        pkH.x = cvtpk(pH[0], pH[1]); pkH.y = cvtpk(pH[2], pH[3]);
        pkH.z = cvtpk(pH[4], pH[5]); pkH.w = cvtpk(pH[6], pH[7]);
        *(uint4*)&Pw[r * 40 + c8]       = pkL;   // 16B-aligned (stride 80B)
        *(uint4*)&Pw[640 + r * 40 + c8] = pkH;

        // A-frags via same-wave LDS transpose (lgkm-only), B-frags from regs
        const bf16x8 afL = *(const bf16x8*)&Pw[m16 * 40 + q4 * 8];
        const bf16x8 afH = *(const bf16x8*)&Pw[640 + m16 * 40 + q4 * 8];
        #pragma unroll
        for (int fg = 0; fg < 8; fg++) {
            acc[0][fg] = __builtin_amdgcn_mfma_f32_16x16x32_bf16(afL, Bf[fg], acc[0][fg], 0, 0, 0);
            acc[1][fg] = __builtin_amdgcn_mfma_f32_16x16x32_bf16(afH, Bf[fg], acc[1][fg], 0, 0, 0);
        }
    };

    #pragma unroll 1
    for (int t = 0; t < 32; t += 2) {
        body(t,     aA0, aA1, aA2, aA3);
        body(t + 1, aB0, aB1, aB2, aB3);
    }

    // Z: lanes 4r..4r+3 hold row r (low) and r+16 (high) partials
    zL += __shfl_xor(zL, 1, 64);
    zL += __shfl_xor(zL, 2, 64);
    zH += __shfl_xor(zH, 1, 64);
    zH += __shfl_xor(zH, 2, 64);
    if ((lane & 3) == 0) {
        Zl[wave][r]      = zL;
        Zl[wave][r + 16] = zH;
    }
    __syncthreads();

    const int er = tid >> 4;            // epilogue row 0..31
    const int ef = (tid & 15) * 2;      // feat pair within 32-feat quarter
    float zs = 0.f;
    #pragma unroll
    for (int wv = 0; wv < 8; wv++) zs += Zl[wv][er];
    const float zinv = 1.0f / zs;

    #pragma unroll
    for (int qp = 0; qp < 4; qp++) {    // cross-wave O reduce, 32 feats/pass
        #pragma unroll
        for (int g = 0; g < 2; g++) {   // C layout: col=lane&15, row=q4*4+v
            const int fg = qp * 2 + g;
            #pragma unroll
            for (int rh = 0; rh < 2; rh++)
                #pragma unroll
                for (int v = 0; v < 4; v++)
                    Ol[wave][rh * 16 + q4 * 4 + v][g * 16 + m16] = acc[rh][fg][v];
        }
        __syncthreads();
        float o0 = 0.f, o1 = 0.f;
        #pragma unroll
        for (int wv = 0; wv < 8; wv++) {
            o0 += Ol[wv][er][ef];
            o1 += Ol[wv][er][ef + 1];
        }
        *(float2*)&out[(size_t)(i0 + er) * GF + qp * 32 + ef] =
            make_float2(o0 * zinv, o1 * zinv);
        __syncthreads();
    }
}

extern "C" void kernel_launch(void* const* d_in, const int* in_sizes, int n_in,
                              void* d_out, int out_size, void* d_ws, size_t ws_size,
                              hipStream_t stream)
{
    (void)in_sizes; (void)n_in; (void)out_size; (void)ws_size;
    const float* adj  = (const float*)d_in[0];
    const float* x    = (const float*)d_in[1];
    const float* w    = (const float*)d_in[2];
    const float* bias = (const float*)d_in[3];
    const float* phi  = (const float*)d_in[4];
    float* out = (float*)d_out;

    char* ws = (char*)d_ws;
    unsigned short* xpt = (unsigned short*)ws;             // 2 MB bf16 x' swizzled
    float* s_src = (float*)(ws + (size_t)GF * GN * 2);     // 32 KB (log2e-scaled)
    float* s_dst = s_src + GN;                             // 32 KB (log2e-scaled)
    unsigned* Dkey = (unsigned*)(s_dst + GN);              // 4 B

    hipMemsetAsync(Dkey, 0, sizeof(unsigned), stream);
    gat_k1 <<<GN / 16, 256, 0, stream>>>(x, w, bias, phi, xpt, s_src, s_dst);
    gat_k1b<<<8, 256, 0, stream>>>(s_dst, Dkey);
    gat_k2 <<<GN / 32, 512, 0, stream>>>(adj, xpt, s_src, s_dst, Dkey, out);
}